// Round 7
// baseline (259.222 us; speedup 1.0000x reference)
//
#include <hip/hip_runtime.h>
#include <hip/hip_bf16.h>

typedef __attribute__((ext_vector_type(8))) short short8;
typedef __attribute__((ext_vector_type(4))) float floatx4;
typedef __attribute__((ext_vector_type(16))) float floatx16;

#define BATCH 8
#define SEQ 2048
#define DMODEL 768
#define NQKV 2304
#define SCALE 0.03608439182435161f

__device__ __forceinline__ ushort f2bf(float f) {
    union { float f; uint u; } in; in.f = f;
    uint u = in.u;
    return (ushort)((u + 0x7FFFu + ((u >> 16) & 1u)) >> 16);
}
__device__ __forceinline__ float bf2f(ushort h) {
    union { uint u; float f; } o; o.u = ((uint)h) << 16;
    return o.f;
}

// async global->LDS, 16B per lane. lds ptr wave-uniform; HW scatters lane*16.
__device__ __forceinline__ void async_copy16(void* lds_uniform, const void* gaddr) {
    __builtin_amdgcn_global_load_lds(
        (const __attribute__((address_space(1))) void*)gaddr,
        (__attribute__((address_space(3))) void*)lds_uniform,
        16, 0, 0);
}

#define BARRIER() asm volatile("s_barrier" ::: "memory")
#define LGKM0()   do { asm volatile("s_waitcnt lgkmcnt(0)" ::: "memory"); \
                       __builtin_amdgcn_sched_barrier(0); } while (0)
#define LGKM_HINT() asm volatile("s_waitcnt lgkmcnt(8)" ::: "memory")
#define VMCNT(n)  asm volatile("s_waitcnt vmcnt(" #n ")" ::: "memory")

// ---------------------------------------------------------------------------
// 256x256 8-phase GEMM template. BK=64, 2 K-tiles/iter, 8 waves (2M x 4N),
// 128KB dynamic LDS (2 dbuf x (A 32KB + B 32KB)), global_load_lds staging
// with source-side chunk-XOR swizzle (slot = c ^ (row&7); 0 conflicts, R3).
// R7: MFMA 32x32x16 (2495 TF ceiling vs 2075 for 16x16x32, m119). Per wave:
// 4 m-frags x 2 n-frags of 32; C/D layout col=lane&31,
// row=(r&3)+8*(r>>2)+4*(lane>>5)  [m74/m101].
// MODE 0: qkv (bias; Q/K row-major bf16; V stored TRANSPOSED to Vt).
// MODE 1: score (bf16 out). MODE 2: pv (fp32 out).
// Epilogue: row-major per-wave scratch [64][36] fp32 — scalar ds_write
// (<=2-way, free) + contiguous ds_read_b128 -> dense coalesced stores.
// V-quadrants bypass LDS (fragment-native 8B stores).
// ---------------------------------------------------------------------------
template<int MODE, int KT>
__global__ __launch_bounds__(512, 2) void gemm8(
    const ushort* __restrict__ A, const ushort* __restrict__ B,
    const float* __restrict__ bias,
    void* __restrict__ out0, void* __restrict__ out1, void* __restrict__ out2,
    int lda, int ldb)
{
    extern __shared__ __align__(16) ushort lds[];
    const int tid  = threadIdx.x;
    const int w    = tid >> 6, lane = tid & 63;
    const int wr   = w >> 2,  wc   = w & 3;      // wave row(0-1) / col(0-3)
    const int l31  = lane & 31, hi = lane >> 5;  // frag row/col, k-half
    const int srow = lane >> 3;                  // staging: row within 8-row chunk
    const int scc  = (lane & 7) ^ srow;          // staging: swizzled src chunk

    const int m0 = blockIdx.x * 256, n0 = blockIdx.y * 256;
    const ushort* Abase;
    const ushort* Bbase;
    if (MODE == 0) {
        Abase = A + (size_t)m0 * lda;
        Bbase = B + (size_t)n0 * ldb;
    } else if (MODE == 1) {
        const int b = blockIdx.z;
        Abase = A + ((size_t)(b * SEQ + m0)) * lda;
        Bbase = B + ((size_t)(b * SEQ + n0)) * ldb;
    } else {
        const int b = blockIdx.z;
        Abase = A + (size_t)b * SEQ * SEQ + (size_t)m0 * lda;
        Bbase = B + (size_t)b * DMODEL * SEQ + (size_t)n0 * ldb;
    }

    // LDS layout (ushort units): buf0 A @0, buf0 B @16384, buf1 A @32768, buf1 B @49152
    const ushort* At[2] = { lds,         lds + 32768 };
    const ushort* Bt[2] = { lds + 16384, lds + 49152 };

    // Stage one half-tile (16KB): 2 gload_lds per thread. A halves: alpha = rows
    // [0,64)u[128,192) (the mh=0 rows), beta = the rest. B halves: cols ==
    // [0,32) mod 64 (alpha = nh0 bands) / [32,64) mod 64 (beta).
    #define STG(tile, mat, half) do { if ((tile) < KT) {                          \
        ushort* sb_ = lds + (((tile) & 1) ? 32768 : 0) + ((mat) ? 16384 : 0);     \
        const ushort* g_ = (mat) ? Bbase : Abase;                                 \
        const size_t ld_ = (mat) ? (size_t)ldb : (size_t)lda;                     \
        const int k0_ = (tile) << 6;                                              \
        _Pragma("unroll")                                                         \
        for (int t_ = 0; t_ < 2; ++t_) {                                          \
            const int c8_ = (mat) ? ((w & 3) + ((w >> 2) << 3) + (t_ << 4) + ((half) << 2)) \
                                  : (w + (t_ << 4) + ((half) << 3));              \
            const int row_ = (c8_ << 3) + srow;                                   \
            async_copy16(sb_ + c8_ * 512, g_ + (size_t)row_ * ld_ + k0_ + scc * 8); \
        } } } while (0)

    short8 af[2][4], bf[2][4];
    floatx16 acc[4][2] = {};

    #define LDFRAG(tp, row, c) \
        (*reinterpret_cast<const short8*>(&(tp)[((row) << 6) + ((((c) ^ ((row) & 7))) << 3)]))

    // A frag (32x16): row = base + l31, k-chunk = kk*2 + hi
    #define READ_A(bufi, mh) do {                                                 \
        _Pragma("unroll") for (int mf_ = 0; mf_ < 2; ++mf_)                       \
        _Pragma("unroll") for (int kk_ = 0; kk_ < 4; ++kk_)                       \
            af[mf_][kk_] = LDFRAG(At[bufi], wr * 128 + (mh) * 64 + mf_ * 32 + l31, kk_ * 2 + hi); \
    } while (0)
    #define READ_B(bufi, nh) do {                                                 \
        _Pragma("unroll") for (int kk_ = 0; kk_ < 4; ++kk_)                       \
            bf[nh][kk_] = LDFRAG(Bt[bufi], wc * 64 + (nh) * 32 + l31, kk_ * 2 + hi); \
    } while (0)
    #define MFMA_Q(mh, nh) do {                                                   \
        __builtin_amdgcn_s_setprio(1);                                            \
        _Pragma("unroll") for (int mf_ = 0; mf_ < 2; ++mf_)                       \
        _Pragma("unroll") for (int kk_ = 0; kk_ < 4; ++kk_)                       \
            acc[(mh) * 2 + mf_][nh] = __builtin_amdgcn_mfma_f32_32x32x16_bf16(    \
                af[mf_][kk_], bf[nh][kk_], acc[(mh) * 2 + mf_][nh], 0, 0, 0);     \
        __builtin_amdgcn_s_setprio(0);                                            \
    } while (0)

    // Prologue: tile0 fully + tile1 {A-a, B-a, B-b}. 14 loads; vmcnt(6) -> tile0 resident.
    STG(0, 0, 0); STG(0, 1, 0); STG(0, 1, 1); STG(0, 0, 1);
    STG(1, 0, 0); STG(1, 1, 0); STG(1, 1, 1);
    VMCNT(6);
    BARRIER();

    #pragma unroll 1
    for (int it = 0; it < KT / 2; ++it) {
        const int t = 2 * it;
        const bool lastit = (it == KT / 2 - 1);
        // ---- K-tile t (buf 0) ----
        // P1
        READ_A(0, 0); READ_B(0, 0);
        STG(t + 1, 0, 1);
        LGKM_HINT();
        BARRIER(); LGKM0();
        MFMA_Q(0, 0);
        BARRIER();
        // P2
        READ_B(0, 1);
        STG(t + 2, 0, 0);
        BARRIER(); LGKM0();
        MFMA_Q(0, 1);
        BARRIER();
        // P3
        READ_A(0, 1);
        STG(t + 2, 1, 0);
        BARRIER(); LGKM0();
        MFMA_Q(1, 0);
        BARRIER();
        // P4
        STG(t + 2, 1, 1);
        BARRIER();
        MFMA_Q(1, 1);
        if (lastit) { VMCNT(0); } else { VMCNT(6); }
        BARRIER();
        // ---- K-tile t+1 (buf 1) ----
        // P5
        READ_A(1, 0); READ_B(1, 0);
        STG(t + 2, 0, 1);
        LGKM_HINT();
        BARRIER(); LGKM0();
        MFMA_Q(0, 0);
        BARRIER();
        // P6
        READ_B(1, 1);
        STG(t + 3, 0, 0);
        BARRIER(); LGKM0();
        MFMA_Q(0, 1);
        BARRIER();
        // P7
        READ_A(1, 1);
        STG(t + 3, 1, 0);
        BARRIER(); LGKM0();
        MFMA_Q(1, 0);
        BARRIER();
        // P8
        STG(t + 3, 1, 1);
        BARRIER();
        MFMA_Q(1, 1);
        VMCNT(6);
        BARRIER();
    }

    // ---- Epilogue ----
    // Safe: after final P8 barrier all waves are past every staging read and
    // VMCNT(0) (last iter P4) drained all global_load_lds writes.
    const int mrow = m0 + wr * 128;
    const int ncol = n0 + wc * 64;

    if (MODE == 0 && blockIdx.y >= 6) {
        // V quadrant: fragment-native transposed store straight to Vt[b][d][n].
        // m = mf*32 + g*8 + hi*4 + (r&3): per d-row, 2 lanes x 4 g cover 32
        // consecutive m (64B) -> L2 aggregates.
        ushort* Vt = (ushort*)out2;
        const int bIdx = m0 >> 11;        // batch (tiles never straddle: 2048%256==0)
        const int ns0  = m0 & 2047;       // seq offset within batch
        #pragma unroll
        for (int nf = 0; nf < 2; ++nf) {
            const int e = ncol + nf * 32 + l31;       // 1536..2303
            const int d = e - 2 * DMODEL;
            const float bv = bias[e];
            ushort* vrow = Vt + ((size_t)bIdx * DMODEL + d) * SEQ + ns0;
            #pragma unroll
            for (int mf = 0; mf < 4; ++mf) {
                const floatx16 v = acc[mf][nf];
                #pragma unroll
                for (int g = 0; g < 4; ++g) {
                    uint2 u;
                    u.x = (uint)f2bf(v[g * 4 + 0] + bv) | ((uint)f2bf(v[g * 4 + 1] + bv) << 16);
                    u.y = (uint)f2bf(v[g * 4 + 2] + bv) | ((uint)f2bf(v[g * 4 + 3] + bv) << 16);
                    *reinterpret_cast<uint2*>(vrow + wr * 128 + mf * 32 + g * 8 + hi * 4) = u;
                }
            }
        }
    } else {
        // Row-major per-wave scratch [64 rows][stride 36] fp32 = 9216 B.
        // Write: scalar ds_write_b32; lanes 0-31 cover 32 consecutive cols,
        // lanes 32-63 shifted rows (+4*36 = +16 banks) -> <=2 lanes/bank (free).
        // Read: contiguous ds_read_b128 (8 lanes/quad = dense).
        float* scr = reinterpret_cast<float*>(reinterpret_cast<char*>(lds) + (size_t)w * 9216);
        #pragma unroll
        for (int mh = 0; mh < 2; ++mh) {
            #pragma unroll
            for (int np = 0; np < 2; ++np) {
                #pragma unroll
                for (int mf2 = 0; mf2 < 2; ++mf2) {
                    const floatx16 v = acc[mh * 2 + mf2][np];
                    #pragma unroll
                    for (int r = 0; r < 16; ++r) {
                        const int rq = mf2 * 32 + (r & 3) + 8 * (r >> 2) + 4 * hi;
                        scr[rq * 36 + l31] = v[r];
                    }
                }
                asm volatile("s_waitcnt lgkmcnt(0)" ::: "memory");
                __builtin_amdgcn_sched_barrier(0);

                if (MODE == 2) {
                    float* Ob = (float*)out0 + (size_t)blockIdx.z * SEQ * DMODEL;
                    const int c4 = (lane & 7) * 4;
                    #pragma unroll
                    for (int p = 0; p < 8; ++p) {
                        const int row = p * 8 + (lane >> 3);
                        const float4 v = *reinterpret_cast<const float4*>(&scr[row * 36 + c4]);
                        *reinterpret_cast<float4*>(
                            &Ob[(size_t)(mrow + mh * 64 + row) * DMODEL + ncol + np * 32 + c4]) = v;
                    }
                } else {
                    const int c8 = (lane & 3) * 8;
                    const int e0 = ncol + np * 32 + c8;
                    ushort* dst; int ec; float mul;
                    float bs[8] = {0, 0, 0, 0, 0, 0, 0, 0};
                    if (MODE == 0) {
                        const bool isQ = e0 < DMODEL;
                        dst = isQ ? (ushort*)out0 : (ushort*)out1;
                        ec  = isQ ? e0 : e0 - DMODEL;
                        mul = isQ ? SCALE : 1.0f;
                        const float4 b0 = *reinterpret_cast<const float4*>(&bias[e0]);
                        const float4 b1 = *reinterpret_cast<const float4*>(&bias[e0 + 4]);
                        bs[0] = b0.x * mul; bs[1] = b0.y * mul;
                        bs[2] = b0.z * mul; bs[3] = b0.w * mul;
                        bs[4] = b1.x * mul; bs[5] = b1.y * mul;
                        bs[6] = b1.z * mul; bs[7] = b1.w * mul;
                    } else {
                        dst = (ushort*)out0 + (size_t)blockIdx.z * SEQ * SEQ;
                        ec = e0; mul = 1.0f;
                    }
                    const size_t ostride = (MODE == 0) ? (size_t)DMODEL : (size_t)SEQ;
                    #pragma unroll
                    for (int p = 0; p < 4; ++p) {
                        const int row = p * 16 + (lane >> 2);
                        const float4 lo = *reinterpret_cast<const float4*>(&scr[row * 36 + c8]);
                        const float4 hi4 = *reinterpret_cast<const float4*>(&scr[row * 36 + c8 + 4]);
                        short8 o;
                        o[0] = (short)f2bf(lo.x * mul + bs[0]);
                        o[1] = (short)f2bf(lo.y * mul + bs[1]);
                        o[2] = (short)f2bf(lo.z * mul + bs[2]);
                        o[3] = (short)f2bf(lo.w * mul + bs[3]);
                        o[4] = (short)f2bf(hi4.x * mul + bs[4]);
                        o[5] = (short)f2bf(hi4.y * mul + bs[5]);
                        o[6] = (short)f2bf(hi4.z * mul + bs[6]);
                        o[7] = (short)f2bf(hi4.w * mul + bs[7]);
                        *reinterpret_cast<short8*>(
                            &dst[(size_t)(mrow + mh * 64 + row) * ostride + ec]) = o;
                    }
                }
                // Reads must complete before this wave rewrites its region.
                asm volatile("s_waitcnt lgkmcnt(0)" ::: "memory");
                __builtin_amdgcn_sched_barrier(0);
            }
        }
    }
    #undef STG
    #undef LDFRAG
    #undef READ_A
    #undef READ_B
    #undef MFMA_Q
}

// ---------------------------------------------------------------------------
// Kernel 0a: X fp32 -> bf16
// ---------------------------------------------------------------------------
__global__ __launch_bounds__(256) void convert_x(const float* __restrict__ X,
                                                 ushort* __restrict__ Xb) {
    const int total = (BATCH * SEQ * DMODEL) / 8;
    for (int i = blockIdx.x * 256 + threadIdx.x; i < total; i += gridDim.x * 256) {
        const float4 v0 = reinterpret_cast<const float4*>(X)[(size_t)i * 2];
        const float4 v1 = reinterpret_cast<const float4*>(X)[(size_t)i * 2 + 1];
        uint4 u;
        u.x = (uint)f2bf(v0.x) | ((uint)f2bf(v0.y) << 16);
        u.y = (uint)f2bf(v0.z) | ((uint)f2bf(v0.w) << 16);
        u.z = (uint)f2bf(v1.x) | ((uint)f2bf(v1.y) << 16);
        u.w = (uint)f2bf(v1.z) | ((uint)f2bf(v1.w) << 16);
        reinterpret_cast<uint4*>(Xb)[i] = u;
    }
}

// ---------------------------------------------------------------------------
// Kernel 0b: W [768][2304] fp32 -> Wt [2304][768] bf16 (transpose)
// ---------------------------------------------------------------------------
__global__ __launch_bounds__(256) void convert_wt(const float* __restrict__ W,
                                                  ushort* __restrict__ Wt) {
    __shared__ float tile[32][33];
    const int n0 = blockIdx.x * 32, k0 = blockIdx.y * 32;
    const int tx = threadIdx.x & 31, ty = threadIdx.x >> 5;
    #pragma unroll
    for (int i = 0; i < 32; i += 8)
        tile[ty + i][tx] = W[(size_t)(k0 + ty + i) * NQKV + n0 + tx];
    __syncthreads();
    #pragma unroll
    for (int i = 0; i < 32; i += 8)
        Wt[(size_t)(n0 + ty + i) * DMODEL + k0 + tx] = f2bf(tile[tx][ty + i]);
}

// ---------------------------------------------------------------------------
// Kernel 3: row softmax over 2048, in place, bf16. One block per row.
// ---------------------------------------------------------------------------
__global__ __launch_bounds__(256) void softmax_rows(ushort* __restrict__ S) {
    const int row = blockIdx.x;
    ushort* p = S + (size_t)row * SEQ;
    const int tid = threadIdx.x;
    const int wave = tid >> 6, lane = tid & 63;

    short8 v8 = *reinterpret_cast<const short8*>(p + tid * 8);
    float v[8];
    #pragma unroll
    for (int j = 0; j < 8; ++j) v[j] = bf2f((ushort)v8[j]);
    float mx = v[0];
    #pragma unroll
    for (int j = 1; j < 8; ++j) mx = fmaxf(mx, v[j]);
    #pragma unroll
    for (int off = 32; off >= 1; off >>= 1) mx = fmaxf(mx, __shfl_xor(mx, off));
    __shared__ float redm[4], reds[4];
    if (lane == 0) redm[wave] = mx;
    __syncthreads();
    mx = fmaxf(fmaxf(redm[0], redm[1]), fmaxf(redm[2], redm[3]));

    float e[8], s = 0.f;
    #pragma unroll
    for (int j = 0; j < 8; ++j) { e[j] = __expf(v[j] - mx); s += e[j]; }
    #pragma unroll
    for (int off = 32; off >= 1; off >>= 1) s += __shfl_xor(s, off);
    if (lane == 0) reds[wave] = s;
    __syncthreads();
    s = reds[0] + reds[1] + reds[2] + reds[3];
    float inv = 1.f / s;

    short8 o;
    #pragma unroll
    for (int j = 0; j < 8; ++j) o[j] = (short)f2bf(e[j] * inv);
    *reinterpret_cast<short8*>(p + tid * 8) = o;
}

// ---------------------------------------------------------------------------
extern "C" void kernel_launch(void* const* d_in, const int* in_sizes, int n_in,
                              void* d_out, int out_size, void* d_ws, size_t ws_size,
                              hipStream_t stream) {
    const float* X    = (const float*)d_in[0];
    const float* W    = (const float*)d_in[1];
    const float* bias = (const float*)d_in[2];
    float* Out = (float*)d_out;

    // Workspace layout (bytes), total ~142.6 MiB used:
    //   [0, 67.1M):  S  (scores)  -- aliases Xb [0,25.2M) + Wt [25.2M,28.7M),
    //                                which are dead before score_gemm runs.
    //   [67.1M ...): Q | K | Vt   (25.2M each)
    char* ws = (char*)d_ws;
    ushort* S  = (ushort*)ws;
    ushort* Xb = (ushort*)ws;
    ushort* Wt = (ushort*)(ws + (size_t)BATCH * SEQ * DMODEL * 2);
    ushort* Qs = (ushort*)(ws + (size_t)BATCH * SEQ * SEQ * 2);
    ushort* Kb = Qs + (size_t)BATCH * SEQ * DMODEL;
    ushort* Vt = Kb + (size_t)BATCH * SEQ * DMODEL;

    const int LDSB = 131072;
    (void)hipFuncSetAttribute((const void*)gemm8<0, 12>,
                              hipFuncAttributeMaxDynamicSharedMemorySize, LDSB);
    (void)hipFuncSetAttribute((const void*)gemm8<1, 12>,
                              hipFuncAttributeMaxDynamicSharedMemorySize, LDSB);
    (void)hipFuncSetAttribute((const void*)gemm8<2, 32>,
                              hipFuncAttributeMaxDynamicSharedMemorySize, LDSB);

    convert_x<<<2048, 256, 0, stream>>>(X, Xb);
    convert_wt<<<dim3(NQKV / 32, DMODEL / 32), 256, 0, stream>>>(W, Wt);
    gemm8<0, 12><<<dim3(64, 9), 512, LDSB, stream>>>(
        Xb, Wt, bias, Qs, Kb, Vt, DMODEL, DMODEL);
    gemm8<1, 12><<<dim3(8, 8, 8), 512, LDSB, stream>>>(
        Qs, Kb, nullptr, S, nullptr, nullptr, DMODEL, DMODEL);
    softmax_rows<<<BATCH * SEQ, 256, 0, stream>>>(S);
    gemm8<2, 32><<<dim3(8, 3, 8), 512, LDSB, stream>>>(
        S, Vt, nullptr, Out, nullptr, nullptr, SEQ, SEQ);
}